// Round 3
// baseline (604.476 us; speedup 1.0000x reference)
//
#include <hip/hip_runtime.h>
#include <hip/hip_bf16.h>
#include <hip/hip_cooperative_groups.h>
#include <math.h>

namespace cg = cooperative_groups;

typedef __attribute__((ext_vector_type(8))) short  short8;
typedef __attribute__((ext_vector_type(4))) short  short4v;
typedef __attribute__((ext_vector_type(4))) float  floatx4;

// async global->LDS, 16B per lane; LDS dest = wave-uniform base + lane*16
#define GLD16(gp, lp) __builtin_amdgcn_global_load_lds( \
    (__attribute__((address_space(1))) void*)(void*)(gp), \
    (__attribute__((address_space(3))) void*)(lp), 16, 0, 0)

// ---------------------------------------------------------------------------
// All stage pointers in one struct (single kernel arg for cooperative launch).
// ---------------------------------------------------------------------------
struct FusedArgs {
    const float* x;
    const float* Wq; const float* Wk; const float* Wv;
    const float* bq; const float* bk; const float* bv;
    __hip_bfloat16* xbf;    // [8192][1024]  bf16 cast of x
    __hip_bfloat16* WT3;    // 3x [1024][1024] W^T bf16
    float*          bc;     // [3072] bias concat
    float*          rs;     // [4][2048] rowsum
    __hip_bfloat16* QKV;    // [8192][3072]
    unsigned short* VT;     // [4][1024][2048] V transposed
    __hip_bfloat16* Pu;     // [4][2048][2048] exp(scores) (overlays xbf)
    float*          out;    // [4][2048][1024] fp32
};

// ---------------------------------------------------------------------------
// prep unit (one 256-thread block-unit of work, selected by b):
//   [0, 8192)      : cast x fp32 -> bf16 (4 elems/thread)
//   [8192, 11264)  : W^T + cast for Wq/Wk/Wv -> WT3 (32x32 tiles)
//   [11264, 11276) : bias concat -> bc[3072]
//   [11276]        : zero rowsum[8192]
// ---------------------------------------------------------------------------
__device__ __forceinline__
void prep_unit(int b, int t, float* tile /* [32*33] */, const FusedArgs& P)
{
    if (b < 8192) {
        long i = ((long)b * 256 + t) * 4;
        float4 v = *(const float4*)(P.x + i);
        union { short4v s; __hip_bfloat16 h[4]; } u;
        u.h[0] = __float2bfloat16(v.x);
        u.h[1] = __float2bfloat16(v.y);
        u.h[2] = __float2bfloat16(v.z);
        u.h[3] = __float2bfloat16(v.w);
        *(short4v*)(P.xbf + i) = u.s;
    } else if (b < 11264) {
        const int idx = b - 8192;
        const int zz  = idx >> 10;
        const int rem = idx & 1023;
        const float* src = (zz == 0) ? P.Wq : (zz == 1) ? P.Wk : P.Wv;
        __hip_bfloat16* dst = P.WT3 + (long)zz * 1048576;
        const int c0 = (rem & 31) * 32, r0 = (rem >> 5) * 32;
        const int tx = t & 31, ty = t >> 5;   // (32, 8)
#pragma unroll
        for (int i = 0; i < 4; ++i)
            tile[(ty + 8 * i) * 33 + tx] =
                src[(long)(r0 + ty + 8 * i) * 1024 + c0 + tx];
        __syncthreads();
#pragma unroll
        for (int i = 0; i < 4; ++i)
            dst[(long)(c0 + ty + 8 * i) * 1024 + r0 + tx] =
                __float2bfloat16(tile[tx * 33 + ty + 8 * i]);
        __syncthreads();   // protect tile: next persistent unit rewrites it
    } else if (b < 11276) {
        int i = (b - 11264) * 256 + t;
        P.bc[i] = (i < 1024) ? P.bq[i] : (i < 2048) ? P.bk[i - 1024] : P.bv[i - 2048];
    } else {
#pragma unroll
        for (int i = 0; i < 32; ++i)
            P.rs[t + 256 * i] = 0.f;
    }
}

// ---------------------------------------------------------------------------
// m97-style 128x128 bf16 GEMM tile: C = A[M,K] * Bt[N,K]^T, fp32 acc.
// 4 waves (2x2), 4x4 16x16x32 MFMA, BK=64, global_load_lds width-16 staging,
// XOR chunk swizzle. Tile chosen by flat index f (per-z) + batch z.
// XCD swizzle: f -> xcd=f&7, s=f>>3, compact per-XCD rectangles.
// MODE 1: QKV projection (+bias; V part -> VT transposed via LDS).
// MODE 2: scores -> e=exp(acc*scale) bf16 + rowsum atomics.
// MODE 3: PV -> acc / rowsum, fp32.
// ---------------------------------------------------------------------------
template <int MODE>
__device__ __forceinline__
void gemm_tile(unsigned short* smem /* 16384 shorts */, int f, int z,
               const FusedArgs& P)
{
    // per-mode constant bindings (all fold at compile time)
    const unsigned short* A;
    const unsigned short* Bt;
    int lda, ldb, ldc, K;
    long sA, sB, sC;
    if (MODE == 1) {
        A = (const unsigned short*)P.xbf; Bt = (const unsigned short*)P.WT3;
        lda = 1024; ldb = 1024; ldc = 3072; K = 1024; sA = 0; sB = 0; sC = 0;
    } else if (MODE == 2) {
        A = (const unsigned short*)P.QKV; Bt = (const unsigned short*)P.QKV + 1024;
        lda = 3072; ldb = 3072; ldc = 2048; K = 1024;
        sA = 2048L * 3072; sB = 2048L * 3072; sC = 2048L * 2048;
    } else {
        A = (const unsigned short*)P.Pu; Bt = P.VT;
        lda = 2048; ldb = 2048; ldc = 1024; K = 2048;
        sA = 2048L * 2048; sB = 1024L * 2048; sC = 2048L * 1024;
    }
    A  += (long)z * sA;
    Bt += (long)z * sB;

    unsigned short* As = smem;
    unsigned short* Bs = smem + 8192;

    // ---- XCD-aware tile swizzle ----
    int tx_, ty_;
    {
        const int xcd = f & 7;
        const int s   = f >> 3;
        if (MODE == 1) {        // 24 x 64 tiles -> rect 12x16, rects 2x4
            tx_ = (xcd & 1) * 12 + s % 12;
            ty_ = (xcd >> 1) * 16 + s / 12;
        } else if (MODE == 2) { // 16 x 16 tiles -> rect 4x8, rects 4x2
            tx_ = (xcd & 3) * 4 + (s & 3);
            ty_ = (xcd >> 2) * 8 + (s >> 2);
        } else {                // 8 x 16 tiles -> rect 4x4, rects 2x4
            tx_ = (xcd & 1) * 4 + (s & 3);
            ty_ = (xcd >> 1) * 4 + (s >> 2);
        }
    }
    const int m0 = ty_ * 128;
    const int n0 = tx_ * 128;

    const int t   = threadIdx.x;
    const int w   = t >> 6;
    const int l15 = t & 15;
    const int lq  = (t & 63) >> 4;
    const int wm  = w >> 1;
    const int wn  = w & 1;

    // staging: LDS chunk cid=(r*8+c) <- global chunk (r, c^(r&7)); 16B chunks
    long gOffA[4], gOffB[4];
    int  lOff[4];
#pragma unroll
    for (int i = 0; i < 4; ++i) {
        int cid = i * 256 + t;
        int r   = cid >> 3;
        int c   = cid & 7;
        int cg  = c ^ (r & 7);
        lOff[i]  = cid * 8;
        gOffA[i] = (long)(m0 + r) * lda + cg * 8;
        gOffB[i] = (long)(n0 + r) * ldb + cg * 8;
    }

    floatx4 acc[4][4];
#pragma unroll
    for (int i = 0; i < 4; ++i)
#pragma unroll
        for (int j = 0; j < 4; ++j)
            acc[i][j] = (floatx4){0.f, 0.f, 0.f, 0.f};

    for (int k0 = 0; k0 < K; k0 += 64) {
#pragma unroll
        for (int i = 0; i < 4; ++i) {
            GLD16(A  + gOffA[i] + k0, &As[lOff[i]]);
            GLD16(Bt + gOffB[i] + k0, &Bs[lOff[i]]);
        }
        __syncthreads();   // vmcnt drained -> staging visible

#pragma unroll
        for (int s = 0; s < 2; ++s) {
            short8 af[4], bf[4];
#pragma unroll
            for (int mt = 0; mt < 4; ++mt) {
                int r  = wm * 64 + mt * 16 + l15;
                int cc = (s * 4 + lq) ^ (r & 7);
                af[mt] = *(const short8*)&As[r * 64 + cc * 8];
            }
#pragma unroll
            for (int nt = 0; nt < 4; ++nt) {
                int r  = wn * 64 + nt * 16 + l15;
                int cc = (s * 4 + lq) ^ (r & 7);
                bf[nt] = *(const short8*)&Bs[r * 64 + cc * 8];
            }
#pragma unroll
            for (int mt = 0; mt < 4; ++mt)
#pragma unroll
                for (int nt = 0; nt < 4; ++nt)
                    acc[mt][nt] = __builtin_amdgcn_mfma_f32_16x16x32_bf16(
                        af[mt], bf[nt], acc[mt][nt], 0, 0, 0);
        }
        __syncthreads();   // fragment reads done before next staging
    }

    // ---------------- epilogues (C/D layout: col=lane&15, row=quad*4+reg) ----
    if (MODE == 1) {
        if (n0 < 2048) {
            // Q/K part: plain bf16 store with bias
#pragma unroll
            for (int nt = 0; nt < 4; ++nt) {
                int n = n0 + wn * 64 + nt * 16 + l15;
                float bb = P.bc[n];
#pragma unroll
                for (int mt = 0; mt < 4; ++mt) {
                    int mBase = m0 + wm * 64 + mt * 16 + lq * 4;
#pragma unroll
                    for (int r = 0; r < 4; ++r) {
                        float v = acc[mt][nt][r] + bb;
                        P.QKV[(long)(mBase + r) * ldc + n] = __float2bfloat16(v);
                    }
                }
            }
        } else {
            // V part: transpose via LDS into VT[b][d][s] (d = n-2048, s = m%2048)
            const int  z2  = m0 >> 11;
            const int  s0l = m0 & 2047;
            const int  d0  = n0 - 2048;
            __hip_bfloat16* T = (__hip_bfloat16*)smem;   // [64][136]
#pragma unroll
            for (int p = 0; p < 2; ++p) {
                __syncthreads();
                if (wn == p) {
#pragma unroll
                    for (int nt = 0; nt < 4; ++nt) {
                        int nl = nt * 16 + l15;           // 0..63
                        float bb = P.bc[n0 + p * 64 + nl];
#pragma unroll
                        for (int mt = 0; mt < 4; ++mt)
#pragma unroll
                            for (int r = 0; r < 4; ++r) {
                                int ml = wm * 64 + mt * 16 + lq * 4 + r;
                                T[nl * 136 + ml] =
                                    __float2bfloat16(acc[mt][nt][r] + bb);
                            }
                    }
                }
                __syncthreads();
#pragma unroll
                for (int pass = 0; pass < 4; ++pass) {
                    int row = pass * 16 + (t >> 4);       // 0..63
                    int mc  = (t & 15) * 8;
                    short8 val = *(const short8*)&T[row * 136 + mc];
                    *(short8*)&P.VT[(long)z2 * (1024L * 2048) +
                                    (long)(d0 + p * 64 + row) * 2048 + s0l + mc] = val;
                }
            }
            __syncthreads();   // protect smem before next tile/stage staging
        }
    } else if (MODE == 2) {
        float* rsz = P.rs + (long)z * 2048;
        const float scale = 0.08838834764831845f;
#pragma unroll
        for (int mt = 0; mt < 4; ++mt) {
#pragma unroll
            for (int r = 0; r < 4; ++r) {
                int m = m0 + wm * 64 + mt * 16 + lq * 4 + r;
                float psum = 0.f;
#pragma unroll
                for (int nt = 0; nt < 4; ++nt) {
                    int n = n0 + wn * 64 + nt * 16 + l15;
                    float e = __expf(acc[mt][nt][r] * scale);
                    __hip_bfloat16 eb = __float2bfloat16(e);
                    P.Pu[(long)z * sC + (long)m * ldc + n] = eb;
                    psum += __bfloat162float(eb);   // sum the rounded values
                }
                psum += __shfl_xor(psum, 1);
                psum += __shfl_xor(psum, 2);
                psum += __shfl_xor(psum, 4);
                psum += __shfl_xor(psum, 8);
                if (l15 == 0) atomicAdd(&rsz[m], psum);
            }
        }
    } else {   // MODE 3
        const float* rsz = P.rs + (long)z * 2048;
#pragma unroll
        for (int mt = 0; mt < 4; ++mt) {
            int mBase = m0 + wm * 64 + mt * 16 + lq * 4;
            float inv[4];
#pragma unroll
            for (int r = 0; r < 4; ++r) inv[r] = 1.0f / rsz[mBase + r];
#pragma unroll
            for (int nt = 0; nt < 4; ++nt) {
                int n = n0 + wn * 64 + nt * 16 + l15;
#pragma unroll
                for (int r = 0; r < 4; ++r)
                    P.out[(long)z * sC + (long)(mBase + r) * ldc + n] =
                        acc[mt][nt][r] * inv[r];
            }
        }
    }
}

// ---------------------------------------------------------------------------
// ONE cooperative dispatch: 512 persistent blocks (2/CU guaranteed: 32KB LDS,
// ~64 VGPR), grid.sync between stages. 512 divides every stage exactly:
// prep 11277 units (~22/blk), qkv 1536 tiles (3/blk), score 1024 (2/blk),
// pv 512 (1/blk). f&7 (XCD class) is invariant under the +512 stride.
// ---------------------------------------------------------------------------
__global__ __launch_bounds__(256, 2)
void fused(FusedArgs P)
{
    __shared__ __align__(16) unsigned short smem[16384];   // 32 KB
    const int b = blockIdx.x;
    const int t = threadIdx.x;
    cg::grid_group grid = cg::this_grid();

    // ---- stage 0: prep ----
    for (int u = b; u < 11277; u += 512)
        prep_unit(u, t, (float*)smem, P);
    __threadfence();
    grid.sync();

    // ---- stage 1: QKV projection (1536 tiles) ----
    for (int f0 = b; f0 < 1536; f0 += 512)
        gemm_tile<1>(smem, f0, 0, P);
    __threadfence();
    grid.sync();

    // ---- stage 2: scores + exp + rowsum (4 z x 256 tiles) ----
    for (int f0 = b; f0 < 1024; f0 += 512)
        gemm_tile<2>(smem, f0 & 255, f0 >> 8, P);
    __threadfence();
    grid.sync();

    // ---- stage 3: PV + normalize (4 z x 128 tiles) ----
    gemm_tile<3>(smem, b & 127, b >> 7, P);
}

// ---------------------------------------------------------------------------
// Fallback path: classic 4-dispatch pipeline (identical math) in case the
// cooperative launch is rejected on this runtime.
// ---------------------------------------------------------------------------
__global__ __launch_bounds__(256)
void prepK(FusedArgs P)
{
    __shared__ __align__(16) float tile[32 * 33];
    prep_unit(blockIdx.x, threadIdx.x, tile, P);
}

__global__ __launch_bounds__(256, 2)
void qkvK(FusedArgs P)
{
    __shared__ __align__(16) unsigned short smem[16384];
    gemm_tile<1>(smem, blockIdx.y * gridDim.x + blockIdx.x, 0, P);
}

__global__ __launch_bounds__(256, 2)
void scoreK(FusedArgs P)
{
    __shared__ __align__(16) unsigned short smem[16384];
    gemm_tile<2>(smem, blockIdx.y * gridDim.x + blockIdx.x, blockIdx.z, P);
}

__global__ __launch_bounds__(256, 2)
void pvK(FusedArgs P)
{
    __shared__ __align__(16) unsigned short smem[16384];
    gemm_tile<3>(smem, blockIdx.y * gridDim.x + blockIdx.x, blockIdx.z, P);
}

// ---------------------------------------------------------------------------
// Inputs/outputs fp32. B=4, S=2048, D=1024.
// ws (MB): QKV bf16 [8192][3072] @0 (48) | VT bf16 4x[1024][2048] @48 (16)
//          WT3 @64 (6) | bc @70 (12KB) | rowsum @70+16KB (32KB)
//          xbf @72 (16) | Pu bf16 4x[2048][2048] @72 (32, overlays dead xbf)
// total 104 MB.
// ---------------------------------------------------------------------------
extern "C" void kernel_launch(void* const* d_in, const int* in_sizes, int n_in,
                              void* d_out, int out_size, void* d_ws, size_t ws_size,
                              hipStream_t stream)
{
    char* ws = (char*)d_ws;
    const long MB = 1048576;

    FusedArgs P;
    P.x   = (const float*)d_in[0];
    P.Wq  = (const float*)d_in[1];
    P.bq  = (const float*)d_in[2];
    P.Wk  = (const float*)d_in[3];
    P.bk  = (const float*)d_in[4];
    P.Wv  = (const float*)d_in[5];
    P.bv  = (const float*)d_in[6];
    P.QKV = (__hip_bfloat16*)(ws);
    P.VT  = (unsigned short*)(ws + 48 * MB);
    P.WT3 = (__hip_bfloat16*)(ws + 64 * MB);
    P.bc  = (float*)         (ws + 70 * MB);
    P.rs  = (float*)         (ws + 70 * MB + 16384);
    P.xbf = (__hip_bfloat16*)(ws + 72 * MB);
    P.Pu  = (__hip_bfloat16*)(ws + 72 * MB);   // overlays dead xbf
    P.out = (float*)d_out;

    void* kargs[] = { (void*)&P };
    hipError_t err = hipLaunchCooperativeKernel(
        (const void*)fused, dim3(512, 1, 1), dim3(256, 1, 1), kargs, 0, stream);

    if (err != hipSuccess) {
        // fallback: classic 4-dispatch pipeline
        prepK<<<11277, 256, 0, stream>>>(P);
        qkvK<<<dim3(24, 64, 1), 256, 0, stream>>>(P);
        scoreK<<<dim3(16, 16, 4), 256, 0, stream>>>(P);
        pvK<<<dim3(8, 16, 4), 256, 0, stream>>>(P);
    }
}

// Round 5
// 229.433 us; speedup vs baseline: 2.6346x; 2.6346x over previous
//
#include <hip/hip_runtime.h>
#include <hip/hip_bf16.h>
#include <math.h>

typedef __attribute__((ext_vector_type(8))) short  short8;
typedef __attribute__((ext_vector_type(4))) short  short4v;
typedef __attribute__((ext_vector_type(4))) float  floatx4;

// async global->LDS, 16B per lane; LDS dest = wave-uniform base + lane*16
#define GLD16(gp, lp) __builtin_amdgcn_global_load_lds( \
    (__attribute__((address_space(1))) void*)(void*)(gp), \
    (__attribute__((address_space(3))) void*)(lp), 16, 0, 0)

// ---------------------------------------------------------------------------
// Shared m97-style bf16 GEMM core: C = A[M,K] * Bt[N,K]^T, fp32 acc.
// 128x128 tile, 4 waves (2x2), 4x4 16x16x32 MFMA per wave, BK=64,
// global_load_lds width-16 staging, XOR chunk swizzle -> conflict-free LDS.
// XCD-aware tile swizzle: flat tile f -> xcd=f&7, s=f>>3; compact per-XCD
// rectangles for private-L2 reuse.
// MODE 1: QKV projection (+bias; V part stored transposed into VT via LDS).
// MODE 2: scores -> e=exp(acc*scale) bf16 + rowsum atomics; Pu stores go
//         through an LDS transpose-bounce -> short8 packed stores (the
//         64 scalar 2B stores/thread were the exposed epilogue cost at only
//         2 scheduling rounds).
// MODE 3: PV -> acc / rowsum, fp32, non-temporal stores (out never re-read).
// NOTE (R3 post-mortem): do NOT fuse these into one cooperative kernel —
// grid.sync() cost ~100+ us/sync at 512 blocks on 8-XCD MI355X.
// ---------------------------------------------------------------------------
template <int MODE>
__device__ __forceinline__
void gemm_core(const unsigned short* __restrict__ A,
               const unsigned short* __restrict__ Bt,
               const float* __restrict__ bias,
               void* __restrict__ Cout,
               int lda, int ldb, int ldc, int K,
               long sA, long sB, long sC,
               float scale,
               unsigned short* __restrict__ VT,
               float* __restrict__ rowsum)
{
    __shared__ __align__(16) unsigned short smem[16384];   // 32 KB
    unsigned short* As = smem;
    unsigned short* Bs = smem + 8192;

    const int z = blockIdx.z;
    A  += (long)z * sA;
    Bt += (long)z * sB;

    // ---- XCD-aware tile swizzle (per-z tile counts are multiples of 8) ----
    int tx_, ty_;
    {
        const int GX  = gridDim.x;
        const int f   = blockIdx.y * GX + blockIdx.x;
        const int xcd = f & 7;
        const int s   = f >> 3;
        if (MODE == 1) {        // 24 x 64 tiles -> rect 12x16, rects 2x4
            tx_ = (xcd & 1) * 12 + s % 12;
            ty_ = (xcd >> 1) * 16 + s / 12;
        } else if (MODE == 2) { // 16 x 16 tiles -> rect 4x8, rects 4x2
            tx_ = (xcd & 3) * 4 + (s & 3);
            ty_ = (xcd >> 2) * 8 + (s >> 2);
        } else {                // 8 x 16 tiles -> rect 4x4, rects 2x4
            tx_ = (xcd & 1) * 4 + (s & 3);
            ty_ = (xcd >> 1) * 4 + (s >> 2);
        }
    }
    const int m0 = ty_ * 128;
    const int n0 = tx_ * 128;

    const int t   = threadIdx.x;
    const int w   = t >> 6;
    const int l15 = t & 15;
    const int lq  = (t & 63) >> 4;
    const int wm  = w >> 1;
    const int wn  = w & 1;

    // staging: LDS chunk cid=(r*8+c) <- global chunk (r, c^(r&7)); 16B chunks
    long gOffA[4], gOffB[4];
    int  lOff[4];
#pragma unroll
    for (int i = 0; i < 4; ++i) {
        int cid = i * 256 + t;
        int r   = cid >> 3;
        int c   = cid & 7;
        int cg  = c ^ (r & 7);
        lOff[i]  = cid * 8;
        gOffA[i] = (long)(m0 + r) * lda + cg * 8;
        gOffB[i] = (long)(n0 + r) * ldb + cg * 8;
    }

    floatx4 acc[4][4];
#pragma unroll
    for (int i = 0; i < 4; ++i)
#pragma unroll
        for (int j = 0; j < 4; ++j)
            acc[i][j] = (floatx4){0.f, 0.f, 0.f, 0.f};

    for (int k0 = 0; k0 < K; k0 += 64) {
#pragma unroll
        for (int i = 0; i < 4; ++i) {
            GLD16(A  + gOffA[i] + k0, &As[lOff[i]]);
            GLD16(Bt + gOffB[i] + k0, &Bs[lOff[i]]);
        }
        __syncthreads();   // vmcnt drained -> staging visible

#pragma unroll
        for (int s = 0; s < 2; ++s) {
            short8 af[4], bf[4];
#pragma unroll
            for (int mt = 0; mt < 4; ++mt) {
                int r  = wm * 64 + mt * 16 + l15;
                int cc = (s * 4 + lq) ^ (r & 7);
                af[mt] = *(const short8*)&As[r * 64 + cc * 8];
            }
#pragma unroll
            for (int nt = 0; nt < 4; ++nt) {
                int r  = wn * 64 + nt * 16 + l15;
                int cc = (s * 4 + lq) ^ (r & 7);
                bf[nt] = *(const short8*)&Bs[r * 64 + cc * 8];
            }
#pragma unroll
            for (int mt = 0; mt < 4; ++mt)
#pragma unroll
                for (int nt = 0; nt < 4; ++nt)
                    acc[mt][nt] = __builtin_amdgcn_mfma_f32_16x16x32_bf16(
                        af[mt], bf[nt], acc[mt][nt], 0, 0, 0);
        }
        __syncthreads();   // fragment reads done before next staging
    }

    // ---------------- epilogues (C/D layout: col=lane&15, row=quad*4+reg) ----
    if (MODE == 1) {
        if (n0 < 2048) {
            // Q/K part: plain bf16 store with bias
#pragma unroll
            for (int nt = 0; nt < 4; ++nt) {
                int n = n0 + wn * 64 + nt * 16 + l15;
                float bb = bias[n];
#pragma unroll
                for (int mt = 0; mt < 4; ++mt) {
                    int mBase = m0 + wm * 64 + mt * 16 + lq * 4;
#pragma unroll
                    for (int r = 0; r < 4; ++r) {
                        float v = acc[mt][nt][r] + bb;
                        ((__hip_bfloat16*)Cout)[(long)(mBase + r) * ldc + n] =
                            __float2bfloat16(v);
                    }
                }
            }
        } else {
            // V part: transpose via LDS into VT[b][d][s] (d = n-2048, s = m%2048)
            const int  z2  = m0 >> 11;
            const int  s0l = m0 & 2047;
            const int  d0  = n0 - 2048;
            __hip_bfloat16* T = (__hip_bfloat16*)smem;   // [64][136]
#pragma unroll
            for (int p = 0; p < 2; ++p) {
                __syncthreads();
                if (wn == p) {
#pragma unroll
                    for (int nt = 0; nt < 4; ++nt) {
                        int nl = nt * 16 + l15;           // 0..63
                        float bb = bias[n0 + p * 64 + nl];
#pragma unroll
                        for (int mt = 0; mt < 4; ++mt)
#pragma unroll
                            for (int r = 0; r < 4; ++r) {
                                int ml = wm * 64 + mt * 16 + lq * 4 + r;
                                T[nl * 136 + ml] =
                                    __float2bfloat16(acc[mt][nt][r] + bb);
                            }
                    }
                }
                __syncthreads();
#pragma unroll
                for (int pass = 0; pass < 4; ++pass) {
                    int row = pass * 16 + (t >> 4);       // 0..63
                    int mc  = (t & 15) * 8;
                    short8 val = *(const short8*)&T[row * 136 + mc];
                    *(short8*)&VT[(long)z2 * (1024L * 2048) +
                                  (long)(d0 + p * 64 + row) * 2048 + s0l + mc] = val;
                }
            }
        }
    } else if (MODE == 2) {
        float* rs = rowsum + (long)z * 2048;
        // 1) exp + bf16 round into registers; psum/atomics in IDENTICAL order
        //    to the verified baseline (sums the rounded values).
        unsigned short ebv[4][4][4];   // [mt][nt][r], all static indices
#pragma unroll
        for (int mt = 0; mt < 4; ++mt) {
#pragma unroll
            for (int r = 0; r < 4; ++r) {
                int m = m0 + wm * 64 + mt * 16 + lq * 4 + r;
                float psum = 0.f;
#pragma unroll
                for (int nt = 0; nt < 4; ++nt) {
                    float e = __expf(acc[mt][nt][r] * scale);
                    __hip_bfloat16 eb = __float2bfloat16(e);
                    ebv[mt][nt][r] = *(unsigned short*)&eb;
                    psum += __bfloat162float(eb);   // sum the rounded values
                }
                psum += __shfl_xor(psum, 1);
                psum += __shfl_xor(psum, 2);
                psum += __shfl_xor(psum, 4);
                psum += __shfl_xor(psum, 8);
                if (l15 == 0) atomicAdd(&rs[m], psum);
            }
        }
        // 2) flush Pu via LDS bounce -> short8 packed stores (2 half-tiles).
        //    Writers: waves with wm==p cover all 128 cols of rows [p*64, p*64+64).
        unsigned short* T = smem;      // [64][136] shorts (17.4 KB of 32 KB)
#pragma unroll
        for (int p = 0; p < 2; ++p) {
            __syncthreads();
            if (wm == p) {
#pragma unroll
                for (int mt = 0; mt < 4; ++mt)
#pragma unroll
                    for (int nt = 0; nt < 4; ++nt)
#pragma unroll
                        for (int r = 0; r < 4; ++r)
                            T[(mt * 16 + lq * 4 + r) * 136 +
                              wn * 64 + nt * 16 + l15] = ebv[mt][nt][r];
            }
            __syncthreads();
#pragma unroll
            for (int pass = 0; pass < 4; ++pass) {
                int row = pass * 16 + (t >> 4);           // 0..63
                int c8  = (t & 15) * 8;                   // 0..120
                short8 val = *(const short8*)&T[row * 136 + c8];
                *(short8*)&((unsigned short*)Cout)[(long)z * sC +
                    (long)(m0 + p * 64 + row) * ldc + n0 + c8] = val;
            }
        }
    } else {   // MODE 3
        const float* rs = rowsum + (long)z * 2048;
#pragma unroll
        for (int mt = 0; mt < 4; ++mt) {
            int mBase = m0 + wm * 64 + mt * 16 + lq * 4;
            float inv[4];
#pragma unroll
            for (int r = 0; r < 4; ++r) inv[r] = 1.0f / rs[mBase + r];
#pragma unroll
            for (int nt = 0; nt < 4; ++nt) {
                int n = n0 + wn * 64 + nt * 16 + l15;
#pragma unroll
                for (int r = 0; r < 4; ++r)
                    __builtin_nontemporal_store(
                        acc[mt][nt][r] * inv[r],
                        &((float*)Cout)[(long)z * sC + (long)(mBase + r) * ldc + n]);
            }
        }
    }
}

// ---- distinctly-named wrappers (identical codegen; per-dispatch rocprof) ----
__global__ __launch_bounds__(256, 2)
void qkv128(const unsigned short* __restrict__ A, const unsigned short* __restrict__ Bt,
            const float* __restrict__ bias, void* __restrict__ Cout,
            int lda, int ldb, int ldc, int K, long sA, long sB, long sC,
            float scale, unsigned short* __restrict__ VT, float* __restrict__ rowsum)
{ gemm_core<1>(A, Bt, bias, Cout, lda, ldb, ldc, K, sA, sB, sC, scale, VT, rowsum); }

__global__ __launch_bounds__(256, 2)
void score128(const unsigned short* __restrict__ A, const unsigned short* __restrict__ Bt,
              const float* __restrict__ bias, void* __restrict__ Cout,
              int lda, int ldb, int ldc, int K, long sA, long sB, long sC,
              float scale, unsigned short* __restrict__ VT, float* __restrict__ rowsum)
{ gemm_core<2>(A, Bt, bias, Cout, lda, ldb, ldc, K, sA, sB, sC, scale, VT, rowsum); }

__global__ __launch_bounds__(256, 2)
void pv128(const unsigned short* __restrict__ A, const unsigned short* __restrict__ Bt,
           const float* __restrict__ bias, void* __restrict__ Cout,
           int lda, int ldb, int ldc, int K, long sA, long sB, long sC,
           float scale, unsigned short* __restrict__ VT, float* __restrict__ rowsum)
{ gemm_core<3>(A, Bt, bias, Cout, lda, ldb, ldc, K, sA, sB, sC, scale, VT, rowsum); }

// ---------------------------------------------------------------------------
// mega-prep: one dispatch doing (by blockIdx range):
//   [0, 8192)            : cast x fp32 -> bf16 (4 elems/thread)
//   [8192, 11264)        : W^T + cast for Wq/Wk/Wv -> WT3 (32x32 tiles)
//   [11264, 11276)       : bias concat -> bc[3072]
//   [11276]              : zero rowsum[8192]
// ---------------------------------------------------------------------------
__global__ __launch_bounds__(256)
void prep(const float* __restrict__ x,
          const float* __restrict__ Wq, const float* __restrict__ Wk,
          const float* __restrict__ Wv,
          const float* __restrict__ bq, const float* __restrict__ bk,
          const float* __restrict__ bv,
          __hip_bfloat16* __restrict__ xbf,
          __hip_bfloat16* __restrict__ WT3,
          float* __restrict__ bc,
          float* __restrict__ rs)
{
    __shared__ float tile[32][33];
    const int b = blockIdx.x;
    const int t = threadIdx.x;

    if (b < 8192) {
        long i = ((long)b * 256 + t) * 4;
        float4 v = *(const float4*)(x + i);
        union { short4v s; __hip_bfloat16 h[4]; } u;
        u.h[0] = __float2bfloat16(v.x);
        u.h[1] = __float2bfloat16(v.y);
        u.h[2] = __float2bfloat16(v.z);
        u.h[3] = __float2bfloat16(v.w);
        *(short4v*)(xbf + i) = u.s;
    } else if (b < 8192 + 3072) {
        const int idx = b - 8192;
        const int zz  = idx >> 10;
        const int rem = idx & 1023;
        const float* src = (zz == 0) ? Wq : (zz == 1) ? Wk : Wv;
        __hip_bfloat16* dst = WT3 + (long)zz * 1048576;
        const int c0 = (rem & 31) * 32, r0 = (rem >> 5) * 32;
        const int tx = t & 31, ty = t >> 5;   // (32, 8)
#pragma unroll
        for (int i = 0; i < 4; ++i)
            tile[ty + 8 * i][tx] = src[(long)(r0 + ty + 8 * i) * 1024 + c0 + tx];
        __syncthreads();
#pragma unroll
        for (int i = 0; i < 4; ++i)
            dst[(long)(c0 + ty + 8 * i) * 1024 + r0 + tx] =
                __float2bfloat16(tile[tx][ty + 8 * i]);
    } else if (b < 8192 + 3072 + 12) {
        int i = (b - (8192 + 3072)) * 256 + t;
        bc[i] = (i < 1024) ? bq[i] : (i < 2048) ? bk[i - 1024] : bv[i - 2048];
    } else {
#pragma unroll
        for (int i = 0; i < 32; ++i)
            rs[t + 256 * i] = 0.f;
    }
}

// ---------------------------------------------------------------------------
// Inputs/outputs fp32. B=4, S=2048, D=1024.  4 dispatches total.
// ws (MB): QKV bf16 [8192][3072] @0 (48) | VT bf16 4x[1024][2048] @48 (16)
//          WT3 @64 (6) | bc @70 (12KB) | rowsum @70+16KB (32KB)
//          xbf @72 (16) | Pu bf16 4x[2048][2048] @72 (32, overlays dead xbf)
// total 104 MB.
// ---------------------------------------------------------------------------
extern "C" void kernel_launch(void* const* d_in, const int* in_sizes, int n_in,
                              void* d_out, int out_size, void* d_ws, size_t ws_size,
                              hipStream_t stream)
{
    const float* x  = (const float*)d_in[0];
    const float* Wq = (const float*)d_in[1];
    const float* bq = (const float*)d_in[2];
    const float* Wk = (const float*)d_in[3];
    const float* bk = (const float*)d_in[4];
    const float* Wv = (const float*)d_in[5];
    const float* bv = (const float*)d_in[6];

    char* ws = (char*)d_ws;
    const long MB = 1048576;
    __hip_bfloat16* QKV = (__hip_bfloat16*)(ws);
    unsigned short* VT  = (unsigned short*)(ws + 48 * MB);
    __hip_bfloat16* WT3 = (__hip_bfloat16*)(ws + 64 * MB);
    float*          bc  = (float*)         (ws + 70 * MB);
    float*          rs  = (float*)         (ws + 70 * MB + 16384);
    __hip_bfloat16* xbf = (__hip_bfloat16*)(ws + 72 * MB);
    __hip_bfloat16* Pu  = (__hip_bfloat16*)(ws + 72 * MB);   // overlays dead xbf

    // 1. mega-prep (cast + W^T x3 + bias concat + rowsum zero)
    prep<<<8192 + 3072 + 12 + 1, 256, 0, stream>>>(
        x, Wq, Wk, Wv, bq, bk, bv, xbf, WT3, bc, rs);

    // 2. fused QKV projection (V part written transposed into VT)
    qkv128<<<dim3(24, 64, 1), 256, 0, stream>>>(
        (const unsigned short*)xbf, (const unsigned short*)WT3, bc, QKV,
        1024, 1024, 3072, 1024, 0, 0, 0, 1.f, VT, nullptr);

    // 3. scores + exp + rowsum: Pu_b = exp(Q_b K_b^T / sqrt(128)), bf16
    score128<<<dim3(16, 16, 4), 256, 0, stream>>>(
        (const unsigned short*)QKV, (const unsigned short*)(QKV + 1024),
        nullptr, Pu,
        3072, 3072, 2048, 1024,
        2048L * 3072, 2048L * 3072, 2048L * 2048,
        0.08838834764831845f, nullptr, rs);

    // 4. PV + normalize: out_b = (Pu_b V_b) / rowsum, fp32
    pv128<<<dim3(8, 16, 4), 256, 0, stream>>>(
        (const unsigned short*)Pu, VT, nullptr, (float*)d_out,
        2048, 2048, 1024, 2048,
        2048L * 2048, 1024L * 2048, 2048L * 1024,
        1.f, nullptr, rs);
}